// Round 11
// baseline (89.358 us; speedup 1.0000x reference)
//
#include <hip/hip_runtime.h>

// LossUResidu: loss = mean_{b,vox} [ |A u - b| / mx_b * (1-f) ]
// = [ sum over img==0 voxels of |7pt clamped-neighbor laplacian(u)| ] / mx_b / (B*N).
// mx_b = max over voxels of dv(i)+dv(j)+dv(k) + (img!=0)*C, C = dx^2/eps_needle.
// gt never read. a1 = a2 = 1 (cubic grid).
// R11: single kernel + hierarchical ticket. ROOT CAUSE of R9/R10: mod-wrap
// election with garbage-init counters elects an ARBITRARY arrival (0xAA poison
// => 22nd of 64), so the leader reads unpublished partials. Fix: memset the
// 33 counters (2KB, graph-safe node) so election is exact last-arrival.
// Counters padded to 64B lines; cross-block data via atomic RMWs.

namespace {
constexpr int NDIM  = 128;
constexpr int PL    = NDIM * NDIM;         // i-plane stride (floats)
constexpr int NPS   = NDIM * NDIM * NDIM;  // 2^21 voxels per sample
constexpr int BATCH = 4;
constexpr int BLOCKS_PER_S = 512;
constexpr int NBLOCKS = BATCH * BLOCKS_PER_S;  // 2048 (divisible by 8 XCDs)
constexpr int NXCD   = 8;
constexpr int GSIZE  = 64;                 // blocks per ticket group
constexpr int GROUPS = NBLOCKS / GSIZE;    // 32 (8 per sample, 4 per XCD)
constexpr int CSTRIDE = 16;                // counter stride in uints (64B line)
}

// One row-of-4 stencil (k via lane shuffles, clamped at kv edges).
__device__ __forceinline__ void stencil4(
        const float4& c, const float4& xm, const float4& xp,
        const float4& ym, const float4& yp, float lf_raw, float rg_raw,
        const float4& g, bool klo, bool khi, float dij, const float* dkt,
        float C, float& sum, float& mx) {
    float cc[4] = {c.x, c.y, c.z, c.w};
    float zl[4] = {klo ? c.x : lf_raw, c.x, c.y, c.z};
    float zr[4] = {c.y, c.z, c.w, khi ? c.w : rg_raw};
    float im[4] = {xm.x, xm.y, xm.z, xm.w};
    float ip[4] = {xp.x, xp.y, xp.z, xp.w};
    float jm[4] = {ym.x, ym.y, ym.z, ym.w};
    float jp[4] = {yp.x, yp.y, yp.z, yp.w};
    float gg[4] = {g.x, g.y, g.z, g.w};
#pragma unroll
    for (int t = 0; t < 4; ++t) {
        float lap = (im[t] + ip[t]) + (jm[t] + jp[t]) + (zl[t] + zr[t]) - 6.0f * cc[t];
        bool needle = (gg[t] != 0.0f);          // img is exactly -1/0/+1
        sum += needle ? 0.0f : fabsf(lap);      // |Au-b|: b==0, f_div_eps==0 here
        mx = fmaxf(mx, dij + dkt[t] + (needle ? C : 0.0f));
    }
}

__global__ __launch_bounds__(256, 8) void loss_k(
        const float* __restrict__ u, const float* __restrict__ img,
        float* psum, unsigned* pmaxu,
        unsigned long long* gsum, unsigned* gmaxu,
        unsigned* cnt, float* out, float C) {
    // XCD-chunked bijective swizzle: XCD x owns w in [x*256, (x+1)*256).
    int blk = blockIdx.x;
    int w   = (blk & (NXCD - 1)) * (NBLOCKS / NXCD) + (blk >> 3);

    int b   = w >> 9;                        // / BLOCKS_PER_S
    int q   = w & (BLOCKS_PER_S - 1);
    int t   = threadIdx.x;
    int i0  = q >> 3;                        // i-pair [0,64): planes 2i0, 2i0+1
    int j0  = (q & 7) * 8 + ((t >> 5) & 7);  // j-pair [0,64): rows 2j0, 2j0+1
    int kv  = t & 31;
    int k4  = kv << 2;
    int iA  = 2 * i0;
    int iB  = iA + 1;

    const float* ub = u   + (size_t)b * NPS;
    const float* gb = img + (size_t)b * NPS;
    int base0 = (iA * NDIM + 2 * j0) * NDIM + k4;   // plane A, row A
    int base1 = base0 + PL;                          // plane B, row A

    // invariants
    int ojm = (j0 == 0)  ? 0 : -NDIM;
    int ojp = (j0 == 63) ? 0 :  NDIM;
    int oim = (iA == 0)        ? 0 : -PL;
    int oip = (iB == NDIM - 1) ? 0 :  PL;
    float di0 = (iA == 0)        ? 1.0f : 2.0f;
    float di1 = (iB == NDIM - 1) ? 1.0f : 2.0f;
    float djA = (j0 == 0)  ? 1.0f : 2.0f;
    float djB = (j0 == 63) ? 1.0f : 2.0f;
    float dkt[4] = { (kv == 0) ? 1.0f : 2.0f, 2.0f, 2.0f,
                     (kv == 31) ? 1.0f : 2.0f };
    bool klo = (kv == 0), khi = (kv == 31);

    float sum = 0.0f, mx = 0.0f;

    // ---- phase 0: plane A (plane B centers double as A's xp) ----
    const float* p0 = ub + base0;
    const float* p1 = ub + base1;
    float4 c0A = *(const float4*)p0;
    float4 c0B = *(const float4*)(p0 + NDIM);
    float4 c1A = *(const float4*)p1;
    float4 c1B = *(const float4*)(p1 + NDIM);
    float4 xmA = *(const float4*)(p0 + oim);
    float4 xmB = *(const float4*)(p0 + oim + NDIM);
    float4 ym0 = *(const float4*)(p0 + ojm);
    float4 yp0 = *(const float4*)(p0 + NDIM + ojp);
    const float* g0 = gb + base0;
    float4 g0A = *(const float4*)g0;
    float4 g0B = *(const float4*)(g0 + NDIM);
    {
        float lfA = __shfl_up(c0A.w, 1), rgA = __shfl_down(c0A.x, 1);
        float lfB = __shfl_up(c0B.w, 1), rgB = __shfl_down(c0B.x, 1);
        stencil4(c0A, xmA, c1A, ym0, c0B, lfA, rgA, g0A, klo, khi,
                 di0 + djA, dkt, C, sum, mx);
        stencil4(c0B, xmB, c1B, c0A, yp0, lfB, rgB, g0B, klo, khi,
                 di0 + djB, dkt, C, sum, mx);
    }
    // ---- phase 1: plane B (plane A centers double as B's xm) ----
    float4 xpA = *(const float4*)(p1 + oip);
    float4 xpB = *(const float4*)(p1 + oip + NDIM);
    float4 ym1 = *(const float4*)(p1 + ojm);
    float4 yp1 = *(const float4*)(p1 + NDIM + ojp);
    const float* g1 = gb + base1;
    float4 g1A = *(const float4*)g1;
    float4 g1B = *(const float4*)(g1 + NDIM);
    {
        float lfA = __shfl_up(c1A.w, 1), rgA = __shfl_down(c1A.x, 1);
        float lfB = __shfl_up(c1B.w, 1), rgB = __shfl_down(c1B.x, 1);
        stencil4(c1A, c0A, xpA, ym1, c1B, lfA, rgA, g1A, klo, khi,
                 di1 + djA, dkt, C, sum, mx);
        stencil4(c1B, c0B, xpB, c1A, yp1, lfB, rgB, g1B, klo, khi,
                 di1 + djB, dkt, C, sum, mx);
    }

    // ---- block reduce (write-first) ----
    __shared__ float2 red[256];
    __shared__ int sflag1, sflag2;
    red[t] = make_float2(sum, mx);
    __syncthreads();
    if (t < 64) {
        float2 a = red[t], b2 = red[t + 64], c2 = red[t + 128], d2 = red[t + 192];
        float s = (a.x + b2.x) + (c2.x + d2.x);
        float m = fmaxf(fmaxf(a.y, b2.y), fmaxf(c2.y, d2.y));
#pragma unroll
        for (int off = 32; off > 0; off >>= 1) {
            s += __shfl_down(s, off);
            m = fmaxf(m, __shfl_down(m, off));
        }
        if (t == 0) {
            atomicExch(&psum[w], s);                      // coherent publish
            atomicExch(&pmaxu[w], __float_as_uint(m));
            __threadfence();                              // order data < ticket
            unsigned o1 = atomicAdd(&cnt[(w >> 6) * CSTRIDE], 1u);
            sflag1 = (o1 == GSIZE - 1u);                  // exact last arrival
            sflag2 = 0;
        }
    }
    __syncthreads();                                      // B1

    if (sflag1) {                                         // group leader block
        int g = w >> 6;
        __threadfence();                                  // order ticket < reads
        if (t < 64) {
            // 64 lane-parallel coherent reads (distinct addresses)
            double s2 = (double)atomicAdd(&psum[g * GSIZE + t], 0.0f);
            float  m2 = __uint_as_float(atomicOr(&pmaxu[g * GSIZE + t], 0u));
#pragma unroll
            for (int off = 32; off > 0; off >>= 1) {
                s2 += __shfl_down(s2, off);
                m2 = fmaxf(m2, __shfl_down(m2, off));
            }
            if (t == 0) {
                atomicExch(&gsum[g], (unsigned long long)__double_as_longlong(s2));
                atomicExch(&gmaxu[g], __float_as_uint(m2));
                __threadfence();
                unsigned o2 = atomicAdd(&cnt[GROUPS * CSTRIDE], 1u);
                sflag2 = (o2 == GROUPS - 1u);
            }
        }
    }
    __syncthreads();                                      // B2

    if (sflag2) {                                         // the single final block
        __threadfence();
        if (t < 64) {
            double gs = 0.0; float gm = 1.0f;
            if (t < GROUPS) {
                gs = __longlong_as_double((long long)atomicAdd(&gsum[t], 0ull));
                gm = __uint_as_float(atomicOr(&gmaxu[t], 0u));
            }
            // segmented 8-lane reduce (8 groups per sample, group g -> sample g/8)
#pragma unroll
            for (int off = 1; off <= 4; off <<= 1) {
                gs += __shfl_xor(gs, off);
                gm = fmaxf(gm, __shfl_xor(gm, off));
            }
            double r = gs / (double)gm;                   // valid at lanes 0,8,16,24
            double tot = __shfl(r, 0) + __shfl(r, 8) + __shfl(r, 16) + __shfl(r, 24);
            if (t == 0)
                out[0] = (float)(tot / ((double)BATCH * (double)NPS));
        }
    }
}

extern "C" void kernel_launch(void* const* d_in, const int* in_sizes, int n_in,
                              void* d_out, int out_size, void* d_ws, size_t ws_size,
                              hipStream_t stream) {
    const float* u   = (const float*)d_in[0];  // "output" (field)
    // d_in[1] = "gt": shape-only, never read
    const float* img = (const float*)d_in[2];  // trinary field
    float* out = (float*)d_out;

    char* ws = (char*)d_ws;
    unsigned long long* gsum = (unsigned long long*)ws;  ws += GROUPS * sizeof(unsigned long long);  // 256 B
    float*    psum  = (float*)ws;                        ws += NBLOCKS * sizeof(float);              // 8 KB
    unsigned* pmaxu = (unsigned*)ws;                     ws += NBLOCKS * sizeof(unsigned);           // 8 KB
    unsigned* gmaxu = (unsigned*)ws;                     ws += GROUPS * sizeof(unsigned);            // 128 B
    // counters: 33 x 64B lines, 64B-aligned (offset so far = 16768 B, 64 | 16768)
    unsigned* cnt = (unsigned*)ws;

    const double dx = 2.0 / (NDIM - 1);
    const float  C  = (float)((dx * dx) / 1e-6);         // ~248.0005

    // exact-election prerequisite: counters start at 0 every call (R9/R10 bug)
    hipMemsetAsync(cnt, 0, (GROUPS + 1) * CSTRIDE * sizeof(unsigned), stream);
    hipLaunchKernelGGL(loss_k, dim3(NBLOCKS), dim3(256), 0, stream,
                       u, img, psum, pmaxu, gsum, gmaxu, cnt, out, C);
}

// Round 12
// 18.751 us; speedup vs baseline: 4.7655x; 4.7655x over previous
//
#include <hip/hip_runtime.h>

// LossUResidu: loss = mean_{b,vox} [ |A u - b| / mx_b * (1-f) ]
// = [ sum over img==0 voxels of |7pt clamped-neighbor laplacian(u)| ] / mx_b / (B*N).
// mx_b = max over voxels of dv(i)+dv(j)+dv(k) + (img!=0)*C, C = dx^2/eps_needle.
// gt never read. a1 = a2 = 1 (cubic grid). Two kernels, no global atomics
// (R4/R9/R10/R11: every fused grid-reduction variant loses -- single-address
// atomics serialize ~39ns each; per-block device fences invalidate per-XCD L2
// and triple the stencil's latency exposure).
// R12 = R8 (best: 17.75us) + non-temporal img loads (img is read-once; nt
// keeps it from evicting u's reusable halo lines in the miss-latency-bound loop).

namespace {
constexpr int NDIM  = 128;
constexpr int PL    = NDIM * NDIM;         // i-plane stride (floats)
constexpr int NPS   = NDIM * NDIM * NDIM;  // 2^21 voxels per sample
constexpr int BATCH = 4;
constexpr int BLOCKS_PER_S = 512;
constexpr int NBLOCKS = BATCH * BLOCKS_PER_S;  // 2048 (divisible by 8 XCDs)
constexpr int NXCD = 8;
}

typedef float v4f __attribute__((ext_vector_type(4)));
__device__ __forceinline__ float4 ntload4(const float* p) {
    v4f v = __builtin_nontemporal_load((const v4f*)p);
    return make_float4(v.x, v.y, v.z, v.w);
}

// One row-of-4 stencil (k via lane shuffles, clamped at kv edges).
__device__ __forceinline__ void stencil4(
        const float4& c, const float4& xm, const float4& xp,
        const float4& ym, const float4& yp, float lf_raw, float rg_raw,
        const float4& g, bool klo, bool khi, float dij, const float* dkt,
        float C, float& sum, float& mx) {
    float cc[4] = {c.x, c.y, c.z, c.w};
    float zl[4] = {klo ? c.x : lf_raw, c.x, c.y, c.z};
    float zr[4] = {c.y, c.z, c.w, khi ? c.w : rg_raw};
    float im[4] = {xm.x, xm.y, xm.z, xm.w};
    float ip[4] = {xp.x, xp.y, xp.z, xp.w};
    float jm[4] = {ym.x, ym.y, ym.z, ym.w};
    float jp[4] = {yp.x, yp.y, yp.z, yp.w};
    float gg[4] = {g.x, g.y, g.z, g.w};
#pragma unroll
    for (int t = 0; t < 4; ++t) {
        float lap = (im[t] + ip[t]) + (jm[t] + jp[t]) + (zl[t] + zr[t]) - 6.0f * cc[t];
        bool needle = (gg[t] != 0.0f);          // img is exactly -1/0/+1
        sum += needle ? 0.0f : fabsf(lap);      // |Au-b|: b==0, f_div_eps==0 here
        mx = fmaxf(mx, dij + dkt[t] + (needle ? C : 0.0f));
    }
}

__global__ __launch_bounds__(256, 8) void loss_main_k(
        const float* __restrict__ u, const float* __restrict__ img,
        float* __restrict__ psum, float* __restrict__ pmax, float C) {
    // XCD-chunked swizzle: HW round-robins blockIdx%8 across XCDs; remap so
    // XCD x owns contiguous work indices [x*256, (x+1)*256) (bijective).
    int blk = blockIdx.x;
    int w   = (blk & (NXCD - 1)) * (NBLOCKS / NXCD) + (blk >> 3);

    int b   = w >> 9;                        // / BLOCKS_PER_S
    int q   = w & (BLOCKS_PER_S - 1);
    int t   = threadIdx.x;
    int i0  = q >> 3;                        // i-pair [0,64): planes 2i0, 2i0+1
    int j0  = (q & 7) * 8 + ((t >> 5) & 7);  // j-pair [0,64): rows 2j0, 2j0+1
    int kv  = t & 31;
    int k4  = kv << 2;
    int iA  = 2 * i0;                        // lower plane
    int iB  = iA + 1;                        // upper plane

    const float* ub = u   + (size_t)b * NPS;
    const float* gb = img + (size_t)b * NPS;
    int base0 = (iA * NDIM + 2 * j0) * NDIM + k4;   // plane A, row A
    int base1 = base0 + PL;                          // plane B, row A

    // invariants
    int ojm = (j0 == 0)  ? 0 : -NDIM;
    int ojp = (j0 == 63) ? 0 :  NDIM;
    int oim = (iA == 0)        ? 0 : -PL;    // plane A's i-1 (clamped)
    int oip = (iB == NDIM - 1) ? 0 :  PL;    // plane B's i+1 (clamped)
    float di0 = (iA == 0)        ? 1.0f : 2.0f;
    float di1 = (iB == NDIM - 1) ? 1.0f : 2.0f;
    float djA = (j0 == 0)  ? 1.0f : 2.0f;
    float djB = (j0 == 63) ? 1.0f : 2.0f;
    float dkt[4] = { (kv == 0) ? 1.0f : 2.0f, 2.0f, 2.0f,
                     (kv == 31) ? 1.0f : 2.0f };
    bool klo = (kv == 0), khi = (kv == 31);

    float sum = 0.0f, mx = 0.0f;

    // ---- phase 0: plane A (plane B centers double as A's xp) ----
    const float* p0 = ub + base0;
    const float* p1 = ub + base1;
    float4 c0A = *(const float4*)p0;
    float4 c0B = *(const float4*)(p0 + NDIM);
    float4 c1A = *(const float4*)p1;
    float4 c1B = *(const float4*)(p1 + NDIM);
    float4 xmA = *(const float4*)(p0 + oim);
    float4 xmB = *(const float4*)(p0 + oim + NDIM);
    float4 ym0 = *(const float4*)(p0 + ojm);
    float4 yp0 = *(const float4*)(p0 + NDIM + ojp);
    const float* g0 = gb + base0;
    float4 g0A = ntload4(g0);                // img: read-once -> non-temporal
    float4 g0B = ntload4(g0 + NDIM);

    {
        float lfA = __shfl_up(c0A.w, 1), rgA = __shfl_down(c0A.x, 1);
        float lfB = __shfl_up(c0B.w, 1), rgB = __shfl_down(c0B.x, 1);
        stencil4(c0A, xmA, c1A, ym0, c0B, lfA, rgA, g0A, klo, khi,
                 di0 + djA, dkt, C, sum, mx);
        stencil4(c0B, xmB, c1B, c0A, yp0, lfB, rgB, g0B, klo, khi,
                 di0 + djB, dkt, C, sum, mx);
    }

    // ---- phase 1: plane B (plane A centers double as B's xm) ----
    float4 xpA = *(const float4*)(p1 + oip);
    float4 xpB = *(const float4*)(p1 + oip + NDIM);
    float4 ym1 = *(const float4*)(p1 + ojm);
    float4 yp1 = *(const float4*)(p1 + NDIM + ojp);
    const float* g1 = gb + base1;
    float4 g1A = ntload4(g1);
    float4 g1B = ntload4(g1 + NDIM);

    {
        float lfA = __shfl_up(c1A.w, 1), rgA = __shfl_down(c1A.x, 1);
        float lfB = __shfl_up(c1B.w, 1), rgB = __shfl_down(c1B.x, 1);
        stencil4(c1A, c0A, xpA, ym1, c1B, lfA, rgA, g1A, klo, khi,
                 di1 + djA, dkt, C, sum, mx);
        stencil4(c1B, c0B, xpB, c1A, yp1, lfB, rgB, g1B, klo, khi,
                 di1 + djB, dkt, C, sum, mx);
    }

    // ---- slim write-first block reduce: 1 ds_write_b64/thread, wave0 tree ----
    __shared__ float2 red[256];
    red[t] = make_float2(sum, mx);
    __syncthreads();
    if (t < 64) {
        float2 a = red[t], b2 = red[t + 64], c2 = red[t + 128], d2 = red[t + 192];
        float s = (a.x + b2.x) + (c2.x + d2.x);
        float m = fmaxf(fmaxf(a.y, b2.y), fmaxf(c2.y, d2.y));
#pragma unroll
        for (int off = 32; off > 0; off >>= 1) {
            s += __shfl_down(s, off);
            m = fmaxf(m, __shfl_down(m, off));
        }
        if (t == 0) { psum[w] = s; pmax[w] = m; }   // bijective -> no clash
    }
}

__global__ __launch_bounds__(256) void finalize_k(const float* __restrict__ psum,
                                                  const float* __restrict__ pmax,
                                                  float* __restrict__ out) {
    // one wave per sample; lane reads 8 partials (512/64)
    int wave = threadIdx.x >> 6, lane = threadIdx.x & 63;
    double s = 0.0; float m = 0.0f;
    int base = wave * BLOCKS_PER_S;
#pragma unroll
    for (int r = 0; r < BLOCKS_PER_S / 64; ++r) {
        int idx = base + r * 64 + lane;
        s += (double)psum[idx];
        m = fmaxf(m, pmax[idx]);
    }
#pragma unroll
    for (int off = 32; off > 0; off >>= 1) {
        s += __shfl_down(s, off);
        m = fmaxf(m, __shfl_down(m, off));
    }
    __shared__ double ws[4]; __shared__ float wm[4];
    if (lane == 0) { ws[wave] = s; wm[wave] = m; }
    __syncthreads();
    if (threadIdx.x == 0) {
        double tot = 0.0;
        for (int b = 0; b < BATCH; ++b) tot += ws[b] / (double)wm[b];
        out[0] = (float)(tot / ((double)BATCH * (double)NPS));  // WEIGHT_RESIDU == 1
    }
}

extern "C" void kernel_launch(void* const* d_in, const int* in_sizes, int n_in,
                              void* d_out, int out_size, void* d_ws, size_t ws_size,
                              hipStream_t stream) {
    const float* u   = (const float*)d_in[0];  // "output" (field)
    // d_in[1] = "gt": shape-only, never read
    const float* img = (const float*)d_in[2];  // trinary field
    float* out = (float*)d_out;

    float* psum = (float*)d_ws;                // 2048 floats
    float* pmax = psum + NBLOCKS;              // 2048 floats

    const double dx = 2.0 / (NDIM - 1);
    const float  C  = (float)((dx * dx) / 1e-6);  // ~248.0005

    hipLaunchKernelGGL(loss_main_k, dim3(NBLOCKS), dim3(256), 0, stream,
                       u, img, psum, pmax, C);
    hipLaunchKernelGGL(finalize_k, dim3(1), dim3(256), 0, stream, psum, pmax, out);
}

// Round 13
// 17.921 us; speedup vs baseline: 4.9863x; 1.0463x over previous
//
#include <hip/hip_runtime.h>

// LossUResidu: loss = mean_{b,vox} [ |A u - b| / mx_b * (1-f) ]
// = [ sum over img==0 voxels of |7pt clamped-neighbor laplacian(u)| ] / mx_b / (B*N).
// mx_b = max over voxels of dv(i)+dv(j)+dv(k) + (img!=0)*C, C = dx^2/eps_needle.
// gt never read. a1 = a2 = 1 (cubic grid). Two kernels, no global atomics.
// R13 = exact revert to R8 (best passing: 17.75us).
// Ledger: fusion loses (R4 80us single-atomic drain; R9/R10 ticket-election
// bug; R11 81us device-fence L2 blowout). nt-img loses (R12, -1us: opting out
// of L3 allocation in an L3-resident latency-bound kernel). Traffic/occupancy/
// DS-pipe/L2-locality levers each saturated at <=1us (R5/R6/R7/R8).

namespace {
constexpr int NDIM  = 128;
constexpr int PL    = NDIM * NDIM;         // i-plane stride (floats)
constexpr int NPS   = NDIM * NDIM * NDIM;  // 2^21 voxels per sample
constexpr int BATCH = 4;
constexpr int BLOCKS_PER_S = 512;
constexpr int NBLOCKS = BATCH * BLOCKS_PER_S;  // 2048 (divisible by 8 XCDs)
constexpr int NXCD = 8;
}

// One row-of-4 stencil (k via lane shuffles, clamped at kv edges).
__device__ __forceinline__ void stencil4(
        const float4& c, const float4& xm, const float4& xp,
        const float4& ym, const float4& yp, float lf_raw, float rg_raw,
        const float4& g, bool klo, bool khi, float dij, const float* dkt,
        float C, float& sum, float& mx) {
    float cc[4] = {c.x, c.y, c.z, c.w};
    float zl[4] = {klo ? c.x : lf_raw, c.x, c.y, c.z};
    float zr[4] = {c.y, c.z, c.w, khi ? c.w : rg_raw};
    float im[4] = {xm.x, xm.y, xm.z, xm.w};
    float ip[4] = {xp.x, xp.y, xp.z, xp.w};
    float jm[4] = {ym.x, ym.y, ym.z, ym.w};
    float jp[4] = {yp.x, yp.y, yp.z, yp.w};
    float gg[4] = {g.x, g.y, g.z, g.w};
#pragma unroll
    for (int t = 0; t < 4; ++t) {
        float lap = (im[t] + ip[t]) + (jm[t] + jp[t]) + (zl[t] + zr[t]) - 6.0f * cc[t];
        bool needle = (gg[t] != 0.0f);          // img is exactly -1/0/+1
        sum += needle ? 0.0f : fabsf(lap);      // |Au-b|: b==0, f_div_eps==0 here
        mx = fmaxf(mx, dij + dkt[t] + (needle ? C : 0.0f));
    }
}

__global__ __launch_bounds__(256, 8) void loss_main_k(
        const float* __restrict__ u, const float* __restrict__ img,
        float* __restrict__ psum, float* __restrict__ pmax, float C) {
    // XCD-chunked swizzle: HW round-robins blockIdx%8 across XCDs; remap so
    // XCD x owns contiguous work indices [x*256, (x+1)*256) (bijective).
    int blk = blockIdx.x;
    int w   = (blk & (NXCD - 1)) * (NBLOCKS / NXCD) + (blk >> 3);

    int b   = w >> 9;                        // / BLOCKS_PER_S
    int q   = w & (BLOCKS_PER_S - 1);
    int t   = threadIdx.x;
    int i0  = q >> 3;                        // i-pair [0,64): planes 2i0, 2i0+1
    int j0  = (q & 7) * 8 + ((t >> 5) & 7);  // j-pair [0,64): rows 2j0, 2j0+1
    int kv  = t & 31;
    int k4  = kv << 2;
    int iA  = 2 * i0;                        // lower plane
    int iB  = iA + 1;                        // upper plane

    const float* ub = u   + (size_t)b * NPS;
    const float* gb = img + (size_t)b * NPS;
    int base0 = (iA * NDIM + 2 * j0) * NDIM + k4;   // plane A, row A
    int base1 = base0 + PL;                          // plane B, row A

    // invariants
    int ojm = (j0 == 0)  ? 0 : -NDIM;
    int ojp = (j0 == 63) ? 0 :  NDIM;
    int oim = (iA == 0)        ? 0 : -PL;    // plane A's i-1 (clamped)
    int oip = (iB == NDIM - 1) ? 0 :  PL;    // plane B's i+1 (clamped)
    float di0 = (iA == 0)        ? 1.0f : 2.0f;
    float di1 = (iB == NDIM - 1) ? 1.0f : 2.0f;
    float djA = (j0 == 0)  ? 1.0f : 2.0f;
    float djB = (j0 == 63) ? 1.0f : 2.0f;
    float dkt[4] = { (kv == 0) ? 1.0f : 2.0f, 2.0f, 2.0f,
                     (kv == 31) ? 1.0f : 2.0f };
    bool klo = (kv == 0), khi = (kv == 31);

    float sum = 0.0f, mx = 0.0f;

    // ---- phase 0: plane A (plane B centers double as A's xp) ----
    const float* p0 = ub + base0;
    const float* p1 = ub + base1;
    float4 c0A = *(const float4*)p0;
    float4 c0B = *(const float4*)(p0 + NDIM);
    float4 c1A = *(const float4*)p1;
    float4 c1B = *(const float4*)(p1 + NDIM);
    float4 xmA = *(const float4*)(p0 + oim);
    float4 xmB = *(const float4*)(p0 + oim + NDIM);
    float4 ym0 = *(const float4*)(p0 + ojm);
    float4 yp0 = *(const float4*)(p0 + NDIM + ojp);
    const float* g0 = gb + base0;
    float4 g0A = *(const float4*)g0;
    float4 g0B = *(const float4*)(g0 + NDIM);

    {
        float lfA = __shfl_up(c0A.w, 1), rgA = __shfl_down(c0A.x, 1);
        float lfB = __shfl_up(c0B.w, 1), rgB = __shfl_down(c0B.x, 1);
        stencil4(c0A, xmA, c1A, ym0, c0B, lfA, rgA, g0A, klo, khi,
                 di0 + djA, dkt, C, sum, mx);
        stencil4(c0B, xmB, c1B, c0A, yp0, lfB, rgB, g0B, klo, khi,
                 di0 + djB, dkt, C, sum, mx);
    }

    // ---- phase 1: plane B (plane A centers double as B's xm) ----
    float4 xpA = *(const float4*)(p1 + oip);
    float4 xpB = *(const float4*)(p1 + oip + NDIM);
    float4 ym1 = *(const float4*)(p1 + ojm);
    float4 yp1 = *(const float4*)(p1 + NDIM + ojp);
    const float* g1 = gb + base1;
    float4 g1A = *(const float4*)g1;
    float4 g1B = *(const float4*)(g1 + NDIM);

    {
        float lfA = __shfl_up(c1A.w, 1), rgA = __shfl_down(c1A.x, 1);
        float lfB = __shfl_up(c1B.w, 1), rgB = __shfl_down(c1B.x, 1);
        stencil4(c1A, c0A, xpA, ym1, c1B, lfA, rgA, g1A, klo, khi,
                 di1 + djA, dkt, C, sum, mx);
        stencil4(c1B, c0B, xpB, c1A, yp1, lfB, rgB, g1B, klo, khi,
                 di1 + djB, dkt, C, sum, mx);
    }

    // ---- slim write-first block reduce: 1 ds_write_b64/thread, wave0 tree ----
    __shared__ float2 red[256];
    red[t] = make_float2(sum, mx);
    __syncthreads();
    if (t < 64) {
        float2 a = red[t], b2 = red[t + 64], c2 = red[t + 128], d2 = red[t + 192];
        float s = (a.x + b2.x) + (c2.x + d2.x);
        float m = fmaxf(fmaxf(a.y, b2.y), fmaxf(c2.y, d2.y));
#pragma unroll
        for (int off = 32; off > 0; off >>= 1) {
            s += __shfl_down(s, off);
            m = fmaxf(m, __shfl_down(m, off));
        }
        if (t == 0) { psum[w] = s; pmax[w] = m; }   // bijective -> no clash
    }
}

__global__ __launch_bounds__(256) void finalize_k(const float* __restrict__ psum,
                                                  const float* __restrict__ pmax,
                                                  float* __restrict__ out) {
    // one wave per sample; lane reads 8 partials (512/64)
    int wave = threadIdx.x >> 6, lane = threadIdx.x & 63;
    double s = 0.0; float m = 0.0f;
    int base = wave * BLOCKS_PER_S;
#pragma unroll
    for (int r = 0; r < BLOCKS_PER_S / 64; ++r) {
        int idx = base + r * 64 + lane;
        s += (double)psum[idx];
        m = fmaxf(m, pmax[idx]);
    }
#pragma unroll
    for (int off = 32; off > 0; off >>= 1) {
        s += __shfl_down(s, off);
        m = fmaxf(m, __shfl_down(m, off));
    }
    __shared__ double ws[4]; __shared__ float wm[4];
    if (lane == 0) { ws[wave] = s; wm[wave] = m; }
    __syncthreads();
    if (threadIdx.x == 0) {
        double tot = 0.0;
        for (int b = 0; b < BATCH; ++b) tot += ws[b] / (double)wm[b];
        out[0] = (float)(tot / ((double)BATCH * (double)NPS));  // WEIGHT_RESIDU == 1
    }
}

extern "C" void kernel_launch(void* const* d_in, const int* in_sizes, int n_in,
                              void* d_out, int out_size, void* d_ws, size_t ws_size,
                              hipStream_t stream) {
    const float* u   = (const float*)d_in[0];  // "output" (field)
    // d_in[1] = "gt": shape-only, never read
    const float* img = (const float*)d_in[2];  // trinary field
    float* out = (float*)d_out;

    float* psum = (float*)d_ws;                // 2048 floats
    float* pmax = psum + NBLOCKS;              // 2048 floats

    const double dx = 2.0 / (NDIM - 1);
    const float  C  = (float)((dx * dx) / 1e-6);  // ~248.0005

    hipLaunchKernelGGL(loss_main_k, dim3(NBLOCKS), dim3(256), 0, stream,
                       u, img, psum, pmax, C);
    hipLaunchKernelGGL(finalize_k, dim3(1), dim3(256), 0, stream, psum, pmax, out);
}